// Round 19
// baseline (702.718 us; speedup 1.0000x reference)
//
#include <hip/hip_runtime.h>
#include <hip/hip_cooperative_groups.h>
#include <stdint.h>

namespace cg = cooperative_groups;

#define NEURONS 512
#define SYN     784
#define TIN     500
#define TP      522
#define TPAD    528
#define BATCH   64
#define NCOL    (BATCH*TPAD)   // 33792
#define XW2     18             // xbT words per (b,*,s): word0 guard, 1..16 data, 17 guard
#define NKK     98             // K iterations (6272 / 64)
#define OUTF4   ((BATCH*NEURONS*TP)/4)  // 4,276,224 float4s in out

typedef int i32x4 __attribute__((ext_vector_type(4)));

// ================================================================ one cooperative kernel
// R19: prep -> grid.sync -> fused GEMM (R18 body, ~93% issue-saturated, kept
// verbatim) -> grid.sync -> firescan. Rationale: across R0..R18, total-minus-
// gemm is ~170us while non-gemm kernel work is ~55us -- ~35us/dispatch of
// launch/gap overhead. Single cooperative dispatch removes 2 launches + gaps.
// Grid 1024 (4 blocks/CU guaranteed: LDS ~33KB -> 4/CU; VGPR 64 @ (256,4),
// verified R18); gemm's 1056 tiles done grid-stride.
__global__ __launch_bounds__(256, 4) void k_all(
    const int* __restrict__ w, uint2* __restrict__ apk,
    const float* __restrict__ x, uint32_t* __restrict__ xbT,
    unsigned long long* __restrict__ partial, float* __restrict__ out,
    const int* __restrict__ wk)
{
    __shared__ unsigned char nib[16][128];
    __shared__ uint2 T0[2048];           // taps 0..10 sums, packed u8 x8 (per weight)
    __shared__ uint2 T1[1024];           // taps 11..20
    __shared__ unsigned long long red[128 * 4];
    __shared__ uint2 tapv[21];
    __shared__ int argL[576];
    __shared__ unsigned long long fm[9];

    cg::grid_group grid = cg::this_grid();
    const int tid = threadIdx.x;

    // ---------------- phase 1: prep (grid-stride over 5216 virtual blocks)
    for (int vb = blockIdx.x; vb < 5216; vb += gridDim.x) {
        if (vb < 1568) {
            // A pack: one-hot int8 weights, MFMA-fragment-packed (verified R3/R4).
            int u = vb * 256 + tid;                    // 401408 slots
            int half = u & 1, m = (u >> 1) & 15, quad = (u >> 5) & 3;
            int rowblk = (u >> 7) & 31, kk = u >> 12;
            int n = rowblk * 16 + m;
            int s = kk * 8 + quad * 2 + half;
            int wv = w[n * SYN + s];
            uint2 v;
            v.x = (wv < 4)  ? (1u << (8 * wv))       : 0u;
            v.y = (wv >= 4) ? (1u << (8 * (wv - 4))) : 0u;
            apk[u] = v;
            if (u < NCOL) partial[u] = 0ull;           // fused memset(partial)
        } else if (vb < 4704) {
            // xbitsT: LDS nibble transpose, 16 rows per vblock.
            int r0 = (vb - 1568) * 16;                 // 3136 vblocks
            __syncthreads();                           // nib reuse across vb iters
            for (int e = tid; e < 2048; e += 256) {
                int row = e >> 7, q4 = e & 127;
                unsigned char v = 0;
                if (q4 < 125) {
                    float4 f = *(const float4*)(x + (size_t)(r0 + row) * TIN + q4 * 4);
                    v = (unsigned char)((f.x != 0.f) | ((f.y != 0.f) << 1) |
                                        ((f.z != 0.f) << 2) | ((f.w != 0.f) << 3));
                }
                nib[row][q4] = v;
            }
            __syncthreads();
            int row = tid >> 4, d = tid & 15;
            uint64_t u = *(const uint64_t*)&nib[row][d * 8];
            uint32_t wd = 0;
#pragma unroll
            for (int q = 0; q < 8; ++q)
                wd |= ((uint32_t)((u >> (8 * q)) & 0xFull)) << (4 * q);
            if (d == 15) wd &= 0xFFFFFu;               // taus 480..499 only
            int grow = r0 + row;
            int b = grow / SYN, s = grow - b * SYN;
            xbT[(size_t)(b * XW2 + 1 + d) * SYN + s] = wd;
            if (d == 0) {
                xbT[(size_t)(b * XW2) * SYN + s] = 0u;
                xbT[(size_t)(b * XW2 + 17) * SYN + s] = 0u;
            }
        } else {
            // out-zero: 512 vblocks grid-stride over 4,276,224 float4 (68 MB)
            const float4 z = make_float4(0.f, 0.f, 0.f, 0.f);
            float4* out4 = (float4*)out;
            for (size_t i = (size_t)(vb - 4704) * 256 + tid; i < OUTF4; i += 512 * 256)
                out4[i] = z;
        }
    }
    grid.sync();

    // ---------------- phase 2: fused GEMM + argmax (R18 body, grid-stride tiles)
    const int lane = tid & 63;
    const int wn   = tid >> 6;
    const int quad = lane >> 4, l15 = lane & 15;

    // build tables once per block (vb-independent)
    if (tid < 21) {
        uint32_t lo = 0, hi = 0;
        for (int q = 0; q < 4; ++q) {
            lo |= ((uint32_t)wk[q * 21 + tid]) << (8 * q);
            hi |= ((uint32_t)wk[(q + 4) * 21 + tid]) << (8 * q);
        }
        tapv[tid] = make_uint2(lo, hi);
    }
    __syncthreads();
    for (int e = tid; e < 3072; e += 256) {
        int base_t = (e < 2048) ? 0 : 11;
        uint32_t mm = (e < 2048) ? e : (e - 2048);
        uint2 a = make_uint2(0u, 0u);
        while (mm) {
            int p = __builtin_ctz(mm);
            uint2 tv = tapv[base_t + p];
            a.x += tv.x; a.y += tv.y;
            mm &= mm - 1;
        }
        if (e < 2048) T0[e] = a; else T1[e - 2048] = a;
    }
    __syncthreads();

    for (int vb = blockIdx.x; vb < 1056; vb += gridDim.x) {
        // XCD-sibling swizzle (verified R3)
        const int xcd    = vb & 7;
        const int jb     = vb >> 3;
        const int colblk = xcd * 33 + (jb >> 2);       // 0..263
        const int rowblk = jb & 3;

        const int m0   = rowblk * 128;
        const int col0 = colblk * 128;
        const int rb0  = rowblk * 8;

        uint32_t base[2]; uint32_t sh[2];
#pragma unroll
        for (int j = 0; j < 2; ++j) {
            int c = col0 + wn * 32 + j * 16 + l15;
            int b = c / TPAD, t = c - b * TPAD;
            int bp = t + 11;                           // window covers flat bits bp..bp+20
            base[j] = (uint32_t)((b * XW2 + (bp >> 5)) * SYN + quad * 2);
            sh[j]   = (uint32_t)(bp & 31);
        }
        const uint32_t pa0 = (uint32_t)(rb0 * 64 + lane);

        i32x4 acc[8][2];
#pragma unroll
        for (int i = 0; i < 8; ++i)
#pragma unroll
            for (int j = 0; j < 2; ++j) { i32x4 z = {0, 0, 0, 0}; acc[i][j] = z; }

        const i32x4* Apk4 = (const i32x4*)apk;
        for (int kk = 0; kk < NKK; ++kk) {
            i32x4 af[8];
#pragma unroll
            for (int i = 0; i < 8; ++i)
                af[i] = Apk4[pa0 + (uint32_t)kk * 2048 + i * 64];
            i32x4 bf[2];
#pragma unroll
            for (int j = 0; j < 2; ++j) {
                const uint2* px = (const uint2*)(xbT + base[j] + kk * 8);
                uint2 lo = px[0];
                uint2 hi = px[SYN / 2];
                uint32_t win0 = __builtin_amdgcn_alignbit(hi.x, lo.x, sh[j]) & 0x1FFFFFu;
                uint32_t win1 = __builtin_amdgcn_alignbit(hi.y, lo.y, sh[j]) & 0x1FFFFFu;
                uint32_t l0 = win0 & 2047u, h0 = win0 >> 11;
                uint32_t l1 = win1 & 2047u, h1 = win1 >> 11;
                uint2 a0 = make_uint2(0u, 0u), a1 = make_uint2(0u, 0u);
                if (l0) { uint2 u = T0[l0]; a0.x += u.x; a0.y += u.y; }
                if (h0) { uint2 v = T1[h0]; a0.x += v.x; a0.y += v.y; }
                if (l1) { uint2 u = T0[l1]; a1.x += u.x; a1.y += u.y; }
                if (h1) { uint2 v = T1[h1]; a1.x += v.x; a1.y += v.y; }
                i32x4 bb;
                bb[0] = (int)a0.x; bb[1] = (int)a0.y;
                bb[2] = (int)a1.x; bb[3] = (int)a1.y;
                bf[j] = bb;
            }
#pragma unroll
            for (int i = 0; i < 8; ++i)
#pragma unroll
                for (int j = 0; j < 2; ++j)
                    acc[i][j] = __builtin_amdgcn_mfma_i32_16x16x64_i8(af[i], bf[j], acc[i][j], 0, 0, 0);
        }

        // epilogue: per-lane best over its 32 rows, then cross-quad via LDS
#pragma unroll
        for (int j = 0; j < 2; ++j) {
            unsigned long long bp = 0ull;
#pragma unroll
            for (int i = 0; i < 8; ++i)
#pragma unroll
                for (int r = 0; r < 4; ++r) {
                    int grow = m0 + i * 16 + quad * 4 + r;
                    unsigned long long pk =
                        (((unsigned long long)(uint32_t)acc[i][j][r]) << 32) |
                        (unsigned long long)(uint32_t)(511 - grow);
                    bp = pk > bp ? pk : bp;
                }
            red[(wn * 32 + j * 16 + l15) * 4 + quad] = bp;
        }
        __syncthreads();
        if (tid < 128) {
            unsigned long long b = red[tid * 4];
#pragma unroll
            for (int u = 1; u < 4; ++u) {
                unsigned long long v = red[tid * 4 + u];
                b = v > b ? v : b;
            }
            atomicMax(&partial[col0 + tid], b);
        }
        __syncthreads();                               // red reuse fence for next vb
    }
    grid.sync();

    // ---------------- phase 3: firescan (blocks 0..63, one per batch)
    if (blockIdx.x < BATCH) {
        const int b = blockIdx.x;
        const int wv = tid >> 6;
#pragma unroll
        for (int p = 0; p < 3; ++p) {
            int chunk = p * 4 + wv;
            if (chunk < 9) {                           // wave-uniform branch
                int t = chunk * 64 + lane;
                int col = b * TPAD + (t < TPAD ? t : TPAD - 1);
                unsigned long long pv = partial[col];
                int best = (int)(pv >> 32);
                argL[t] = 511 - (int)(pv & 0xFFFFFFFFull);
                unsigned long long f = __ballot((t < TP) && (best > 40));
                if (lane == 0) fm[chunk] = f;
            }
        }
        __syncthreads();
        if (tid == 0) {
            unsigned short ts[26];
            int nf = 0, dep = 0;
            for (int c = 0; c < 9; ++c) {
                unsigned long long mm = fm[c];
                int pos = 0;
                while (pos < 64) {
                    if (dep > 0) {
                        int adv = dep < (64 - pos) ? dep : (64 - pos);
                        dep -= adv; pos += adv; mm >>= adv;  // adv <= 21 < 64
                        continue;
                    }
                    if (mm == 0) break;
                    int z = __builtin_ctzll(mm);
                    pos += z; mm >>= z;
                    ts[nf++] = (unsigned short)(c * 64 + pos);
                    dep = 21; ++pos; mm >>= 1;
                }
            }
            for (int i = 0; i < nf; ++i) {
                int t = ts[i];
                out[(size_t)b * (NEURONS * TP) + (size_t)argL[t] * TP + t] = 1.0f;
            }
        }
    }
}

// ================================================================ fallback path (verified R18, 407us)
__global__ __launch_bounds__(256) void k_prep(
    const int* __restrict__ w, uint2* __restrict__ apk,
    const float* __restrict__ x, uint32_t* __restrict__ xbT,
    unsigned long long* __restrict__ partial, float4* __restrict__ out4)
{
    __shared__ unsigned char nib[16][128];
    const int bid = blockIdx.x, tid = threadIdx.x;
    if (bid < 1568) {
        int u = bid * 256 + tid;
        int half = u & 1, m = (u >> 1) & 15, quad = (u >> 5) & 3;
        int rowblk = (u >> 7) & 31, kk = u >> 12;
        int n = rowblk * 16 + m;
        int s = kk * 8 + quad * 2 + half;
        int wv = w[n * SYN + s];
        uint2 v;
        v.x = (wv < 4)  ? (1u << (8 * wv))       : 0u;
        v.y = (wv >= 4) ? (1u << (8 * (wv - 4))) : 0u;
        apk[u] = v;
        if (u < NCOL) partial[u] = 0ull;
    } else if (bid < 4704) {
        int r0 = (bid - 1568) * 16;
        for (int e = tid; e < 2048; e += 256) {
            int row = e >> 7, q4 = e & 127;
            unsigned char v = 0;
            if (q4 < 125) {
                float4 f = *(const float4*)(x + (size_t)(r0 + row) * TIN + q4 * 4);
                v = (unsigned char)((f.x != 0.f) | ((f.y != 0.f) << 1) |
                                    ((f.z != 0.f) << 2) | ((f.w != 0.f) << 3));
            }
            nib[row][q4] = v;
        }
        __syncthreads();
        int row = tid >> 4, d = tid & 15;
        uint64_t u = *(const uint64_t*)&nib[row][d * 8];
        uint32_t wd = 0;
#pragma unroll
        for (int q = 0; q < 8; ++q)
            wd |= ((uint32_t)((u >> (8 * q)) & 0xFull)) << (4 * q);
        if (d == 15) wd &= 0xFFFFFu;
        int grow = r0 + row;
        int b = grow / SYN, s = grow - b * SYN;
        xbT[(size_t)(b * XW2 + 1 + d) * SYN + s] = wd;
        if (d == 0) {
            xbT[(size_t)(b * XW2) * SYN + s] = 0u;
            xbT[(size_t)(b * XW2 + 17) * SYN + s] = 0u;
        }
    } else {
        const float4 z = make_float4(0.f, 0.f, 0.f, 0.f);
        for (size_t i = (size_t)(bid - 4704) * 256 + tid; i < OUTF4; i += 512 * 256)
            out4[i] = z;
    }
}

__global__ __launch_bounds__(256, 4) void k_gemm_fused2(
    const i32x4*    __restrict__ Apk4,
    const uint32_t* __restrict__ xbT,
    const int*      __restrict__ wk,
    unsigned long long* __restrict__ partial)
{
    __shared__ uint2 T0[2048];
    __shared__ uint2 T1[1024];
    __shared__ unsigned long long red[128 * 4];
    __shared__ uint2 tapv[21];

    const int tid  = threadIdx.x;
    const int lane = tid & 63;
    const int wn   = tid >> 6;
    const int quad = lane >> 4, l15 = lane & 15;

    const int phys   = blockIdx.x;
    const int xcd    = phys & 7;
    const int jb     = phys >> 3;
    const int colblk = xcd * 33 + (jb >> 2);
    const int rowblk = jb & 3;

    const int m0   = rowblk * 128;
    const int col0 = colblk * 128;
    const int rb0  = rowblk * 8;

    if (tid < 21) {
        uint32_t lo = 0, hi = 0;
        for (int q = 0; q < 4; ++q) {
            lo |= ((uint32_t)wk[q * 21 + tid]) << (8 * q);
            hi |= ((uint32_t)wk[(q + 4) * 21 + tid]) << (8 * q);
        }
        tapv[tid] = make_uint2(lo, hi);
    }
    __syncthreads();
    for (int e = tid; e < 3072; e += 256) {
        int base_t = (e < 2048) ? 0 : 11;
        uint32_t mm = (e < 2048) ? e : (e - 2048);
        uint2 a = make_uint2(0u, 0u);
        while (mm) {
            int p = __builtin_ctz(mm);
            uint2 tv = tapv[base_t + p];
            a.x += tv.x; a.y += tv.y;
            mm &= mm - 1;
        }
        if (e < 2048) T0[e] = a; else T1[e - 2048] = a;
    }

    uint32_t base[2]; uint32_t sh[2];
#pragma unroll
    for (int j = 0; j < 2; ++j) {
        int c = col0 + wn * 32 + j * 16 + l15;
        int b = c / TPAD, t = c - b * TPAD;
        int bp = t + 11;
        base[j] = (uint32_t)((b * XW2 + (bp >> 5)) * SYN + quad * 2);
        sh[j]   = (uint32_t)(bp & 31);
    }
    __syncthreads();

    const uint32_t pa0 = (uint32_t)(rb0 * 64 + lane);

    i32x4 acc[8][2];
#pragma unroll
    for (int i = 0; i < 8; ++i)
#pragma unroll
        for (int j = 0; j < 2; ++j) { i32x4 z = {0, 0, 0, 0}; acc[i][j] = z; }

    for (int kk = 0; kk < NKK; ++kk) {
        i32x4 af[8];
#pragma unroll
        for (int i = 0; i < 8; ++i)
            af[i] = Apk4[pa0 + (uint32_t)kk * 2048 + i * 64];
        i32x4 bf[2];
#pragma unroll
        for (int j = 0; j < 2; ++j) {
            const uint2* px = (const uint2*)(xbT + base[j] + kk * 8);
            uint2 lo = px[0];
            uint2 hi = px[SYN / 2];
            uint32_t win0 = __builtin_amdgcn_alignbit(hi.x, lo.x, sh[j]) & 0x1FFFFFu;
            uint32_t win1 = __builtin_amdgcn_alignbit(hi.y, lo.y, sh[j]) & 0x1FFFFFu;
            uint32_t l0 = win0 & 2047u, h0 = win0 >> 11;
            uint32_t l1 = win1 & 2047u, h1 = win1 >> 11;
            uint2 a0 = make_uint2(0u, 0u), a1 = make_uint2(0u, 0u);
            if (l0) { uint2 u = T0[l0]; a0.x += u.x; a0.y += u.y; }
            if (h0) { uint2 v = T1[h0]; a0.x += v.x; a0.y += v.y; }
            if (l1) { uint2 u = T0[l1]; a1.x += u.x; a1.y += u.y; }
            if (h1) { uint2 v = T1[h1]; a1.x += v.x; a1.y += v.y; }
            i32x4 bb;
            bb[0] = (int)a0.x; bb[1] = (int)a0.y;
            bb[2] = (int)a1.x; bb[3] = (int)a1.y;
            bf[j] = bb;
        }
#pragma unroll
        for (int i = 0; i < 8; ++i)
#pragma unroll
            for (int j = 0; j < 2; ++j)
                acc[i][j] = __builtin_amdgcn_mfma_i32_16x16x64_i8(af[i], bf[j], acc[i][j], 0, 0, 0);
    }

#pragma unroll
    for (int j = 0; j < 2; ++j) {
        unsigned long long bp = 0ull;
#pragma unroll
        for (int i = 0; i < 8; ++i)
#pragma unroll
            for (int r = 0; r < 4; ++r) {
                int grow = m0 + i * 16 + quad * 4 + r;
                unsigned long long pk =
                    (((unsigned long long)(uint32_t)acc[i][j][r]) << 32) |
                    (unsigned long long)(uint32_t)(511 - grow);
                bp = pk > bp ? pk : bp;
            }
        red[(wn * 32 + j * 16 + l15) * 4 + quad] = bp;
    }
    __syncthreads();
    if (tid < 128) {
        unsigned long long b = red[tid * 4];
#pragma unroll
        for (int u = 1; u < 4; ++u) {
            unsigned long long v = red[tid * 4 + u];
            b = v > b ? v : b;
        }
        atomicMax(&partial[col0 + tid], b);
    }
}

__global__ __launch_bounds__(256) void k_firescan(
    const unsigned long long* __restrict__ partial, float* __restrict__ out)
{
    __shared__ int argL[576];
    __shared__ unsigned long long fm[9];
    const int b = blockIdx.x, tid = threadIdx.x;
    const int lane = tid & 63, wv = tid >> 6;

#pragma unroll
    for (int p = 0; p < 3; ++p) {
        int chunk = p * 4 + wv;
        if (chunk < 9) {
            int t = chunk * 64 + lane;
            int col = b * TPAD + (t < TPAD ? t : TPAD - 1);
            unsigned long long pv = partial[col];
            int best = (int)(pv >> 32);
            argL[t] = 511 - (int)(pv & 0xFFFFFFFFull);
            unsigned long long f = __ballot((t < TP) && (best > 40));
            if (lane == 0) fm[chunk] = f;
        }
    }
    __syncthreads();

    if (tid == 0) {
        unsigned short ts[26];
        int nf = 0, dep = 0;
        for (int c = 0; c < 9; ++c) {
            unsigned long long mm = fm[c];
            int pos = 0;
            while (pos < 64) {
                if (dep > 0) {
                    int adv = dep < (64 - pos) ? dep : (64 - pos);
                    dep -= adv; pos += adv; mm >>= adv;
                    continue;
                }
                if (mm == 0) break;
                int z = __builtin_ctzll(mm);
                pos += z; mm >>= z;
                ts[nf++] = (unsigned short)(c * 64 + pos);
                dep = 21; ++pos; mm >>= 1;
            }
        }
        for (int i = 0; i < nf; ++i) {
            int t = ts[i];
            out[(size_t)b * (NEURONS * TP) + (size_t)argL[t] * TP + t] = 1.0f;
        }
    }
}

extern "C" void kernel_launch(void* const* d_in, const int* in_sizes, int n_in,
                              void* d_out, int out_size, void* d_ws, size_t ws_size,
                              hipStream_t stream) {
    const float* x      = (const float*)d_in[0];
    const int*   weight = (const int*)d_in[1];
    const int*   wk     = (const int*)d_in[2];

    char* ws = (char*)d_ws;
    uint2*              Apk     = (uint2*)(ws);                        // 3,211,264 B
    uint32_t*           xbT     = (uint32_t*)(ws + 3211264);           // 3,612,672 B
    unsigned long long* partial = (unsigned long long*)(ws + 6823936); //   270,336 B
    // total ws need: 7,094,272 B

    float* out = (float*)d_out;

    // single cooperative dispatch; fallback to verified 3-dispatch path.
    const int* w_a = weight; uint2* apk_a = Apk; const float* x_a = x;
    uint32_t* xbT_a = xbT; unsigned long long* p_a = partial;
    float* out_a = out; const int* wk_a = wk;
    void* kargs[] = { (void*)&w_a, (void*)&apk_a, (void*)&x_a, (void*)&xbT_a,
                      (void*)&p_a, (void*)&out_a, (void*)&wk_a };
    hipError_t e = hipLaunchCooperativeKernel((const void*)k_all, dim3(1024),
                                              dim3(256), kargs, 0, stream);
    if (e != hipSuccess) {
        k_prep<<<5216, 256, 0, stream>>>(weight, Apk, x, xbT, partial, (float4*)out);
        k_gemm_fused2<<<1056, 256, 0, stream>>>((const i32x4*)Apk, xbT, wk, partial);
        k_firescan<<<BATCH, 256, 0, stream>>>(partial, out);
    }
}

// Round 20
// 403.624 us; speedup vs baseline: 1.7410x; 1.7410x over previous
//
#include <hip/hip_runtime.h>
#include <stdint.h>

#define NEURONS 512
#define SYN     784
#define TIN     500
#define TP      522
#define TPAD    528
#define BATCH   64
#define NCOL    (BATCH*TPAD)   // 33792
#define XW2     18             // xbT words per (b,*,s): word0 guard, 1..16 data, 17 guard
#define NKK     98             // K iterations (6272 / 64)
#define OUTF4   ((BATCH*NEURONS*TP)/4)  // 4,276,224 float4s in out

typedef int i32x4 __attribute__((ext_vector_type(4)));

// ---------------------------------------------------------------- prep: A pack + spike bits + partial zero + OUT zero (fused; verified R18)
// blocks 0..1567: apack (+ partial zeroing); 1568..4703: xbitsT; 4704..5215: out-zero.
__global__ __launch_bounds__(256) void k_prep(
    const int* __restrict__ w, uint2* __restrict__ apk,
    const float* __restrict__ x, uint32_t* __restrict__ xbT,
    unsigned long long* __restrict__ partial, float4* __restrict__ out4)
{
    __shared__ unsigned char nib[16][128];
    const int bid = blockIdx.x, tid = threadIdx.x;
    if (bid < 1568) {
        // One-hot int8 weights, MFMA-fragment-packed (verified R3/R4).
        int u = bid * 256 + tid;                       // 401408 slots
        int half = u & 1, m = (u >> 1) & 15, quad = (u >> 5) & 3;
        int rowblk = (u >> 7) & 31, kk = u >> 12;
        int n = rowblk * 16 + m;
        int s = kk * 8 + quad * 2 + half;
        int wv = w[n * SYN + s];
        uint2 v;
        v.x = (wv < 4)  ? (1u << (8 * wv))       : 0u;
        v.y = (wv >= 4) ? (1u << (8 * (wv - 4))) : 0u;
        apk[u] = v;
        if (u < NCOL) partial[u] = 0ull;               // fused memset(partial)
    } else if (bid < 4704) {
        // xbT[(b*18 + word)*784 + s]; word 0,17 guards; LDS nibble transpose.
        int r0 = (bid - 1568) * 16;                    // 3136 blocks
        for (int e = tid; e < 2048; e += 256) {
            int row = e >> 7, q4 = e & 127;
            unsigned char v = 0;
            if (q4 < 125) {
                float4 f = *(const float4*)(x + (size_t)(r0 + row) * TIN + q4 * 4);
                v = (unsigned char)((f.x != 0.f) | ((f.y != 0.f) << 1) |
                                    ((f.z != 0.f) << 2) | ((f.w != 0.f) << 3));
            }
            nib[row][q4] = v;
        }
        __syncthreads();
        int row = tid >> 4, d = tid & 15;
        uint64_t u = *(const uint64_t*)&nib[row][d * 8];
        uint32_t wd = 0;
#pragma unroll
        for (int q = 0; q < 8; ++q)
            wd |= ((uint32_t)((u >> (8 * q)) & 0xFull)) << (4 * q);
        if (d == 15) wd &= 0xFFFFFu;                   // taus 480..499 only
        int grow = r0 + row;
        int b = grow / SYN, s = grow - b * SYN;
        xbT[(size_t)(b * XW2 + 1 + d) * SYN + s] = wd;
        if (d == 0) {
            xbT[(size_t)(b * XW2) * SYN + s] = 0u;     // guard word 0
            xbT[(size_t)(b * XW2 + 17) * SYN + s] = 0u;// guard word 17
        }
    } else {
        // out-zero: 512 blocks, grid-stride over 4,276,224 float4 (68 MB)
        const float4 z = make_float4(0.f, 0.f, 0.f, 0.f);
        for (size_t i = (size_t)(bid - 4704) * 256 + tid; i < OUTF4; i += 512 * 256)
            out4[i] = z;
    }
}

// ---------------------------------------------------------------- fused GEMM + argmax
// R20 = R18 body (228us verified) + SPLIT gather tables. R18's remaining
// measured, addressable term: SQ_LDS_BANK_CONFLICT 2.37e7 ~ 17% of wall.
// uint2 (8B) entries via ds_read_b64 put every entry on an even bank-pair:
// 64 random lanes land on only 16 bank-pairs (avg 4-way, ~N/2.8 cost, m136).
// Split tables T0x/T0y (+T1x/T1y) are 4B-stride over all 32 banks -> random
// indices avg 2-way = free. Cost: 2x ds_read_b32 issues per lookup.
// (R19's cooperative fusion reverted: grid-stride+grid.sync tail quantization
// doubled the GEMM phase; single-dispatch also showed harness overhead is a
// fixed ~120us, not per-dispatch.)
__global__ __launch_bounds__(256, 4) void k_gemm_fused2(
    const i32x4*    __restrict__ Apk4,
    const uint32_t* __restrict__ xbT,
    const int*      __restrict__ wk,
    unsigned long long* __restrict__ partial)
{
    __shared__ uint32_t T0x[2048], T0y[2048];  // taps 0..10 sums, u8x4 lo/hi halves
    __shared__ uint32_t T1x[1024], T1y[1024];  // taps 11..20
    __shared__ unsigned long long red[128 * 4];
    __shared__ uint2 tapv[21];

    const int tid  = threadIdx.x;
    const int lane = tid & 63;
    const int wn   = tid >> 6;
    const int quad = lane >> 4, l15 = lane & 15;

    // XCD-sibling swizzle (verified R3): xbT/Apk L2-hot per XCD.
    const int phys   = blockIdx.x;
    const int xcd    = phys & 7;
    const int jb     = phys >> 3;
    const int colblk = xcd * 33 + (jb >> 2);   // 0..263
    const int rowblk = jb & 3;

    const int m0   = rowblk * 128;
    const int col0 = colblk * 128;
    const int rb0  = rowblk * 8;

    if (tid < 21) {
        uint32_t lo = 0, hi = 0;
        for (int q = 0; q < 4; ++q) {
            lo |= ((uint32_t)wk[q * 21 + tid]) << (8 * q);
            hi |= ((uint32_t)wk[(q + 4) * 21 + tid]) << (8 * q);
        }
        tapv[tid] = make_uint2(lo, hi);
    }
    __syncthreads();
    for (int e = tid; e < 3072; e += 256) {
        int base_t = (e < 2048) ? 0 : 11;
        uint32_t mm = (e < 2048) ? e : (e - 2048);
        uint2 a = make_uint2(0u, 0u);
        while (mm) {
            int p = __builtin_ctz(mm);
            uint2 tv = tapv[base_t + p];
            a.x += tv.x; a.y += tv.y;
            mm &= mm - 1;
        }
        if (e < 2048) { T0x[e] = a.x; T0y[e] = a.y; }
        else          { T1x[e - 2048] = a.x; T1y[e - 2048] = a.y; }
    }

    uint32_t base[2]; uint32_t sh[2];
#pragma unroll
    for (int j = 0; j < 2; ++j) {
        int c = col0 + wn * 32 + j * 16 + l15;
        int b = c / TPAD, t = c - b * TPAD;
        int bp = t + 11;                 // window covers flat bits bp..bp+20
        base[j] = (uint32_t)((b * XW2 + (bp >> 5)) * SYN + quad * 2);
        sh[j]   = (uint32_t)(bp & 31);
    }
    __syncthreads();

    const uint32_t pa0 = (uint32_t)(rb0 * 64 + lane);

    i32x4 acc[8][2];
#pragma unroll
    for (int i = 0; i < 8; ++i)
#pragma unroll
        for (int j = 0; j < 2; ++j) { i32x4 z = {0, 0, 0, 0}; acc[i][j] = z; }

    for (int kk = 0; kk < NKK; ++kk) {
        i32x4 af[8];
#pragma unroll
        for (int i = 0; i < 8; ++i)
            af[i] = Apk4[pa0 + (uint32_t)kk * 2048 + i * 64];
        i32x4 bf[2];
#pragma unroll
        for (int j = 0; j < 2; ++j) {
            const uint2* px = (const uint2*)(xbT + base[j] + kk * 8);
            uint2 lo = px[0];            // word w  : (s0, s1)
            uint2 hi = px[SYN / 2];      // word w+1: (s0, s1)
            uint32_t win0 = __builtin_amdgcn_alignbit(hi.x, lo.x, sh[j]) & 0x1FFFFFu;
            uint32_t win1 = __builtin_amdgcn_alignbit(hi.y, lo.y, sh[j]) & 0x1FFFFFu;
            uint32_t l0 = win0 & 2047u, h0 = win0 >> 11;
            uint32_t l1 = win1 & 2047u, h1 = win1 >> 11;
            uint32_t a0x = 0u, a0y = 0u, a1x = 0u, a1y = 0u;
            if (l0) { a0x += T0x[l0]; a0y += T0y[l0]; }   // T0[0]==0: skip exact
            if (h0) { a0x += T1x[h0]; a0y += T1y[h0]; }
            if (l1) { a1x += T0x[l1]; a1y += T0y[l1]; }
            if (h1) { a1x += T1x[h1]; a1y += T1y[h1]; }
            i32x4 bb;
            bb[0] = (int)a0x; bb[1] = (int)a0y;
            bb[2] = (int)a1x; bb[3] = (int)a1y;
            bf[j] = bb;
        }
#pragma unroll
        for (int i = 0; i < 8; ++i)
#pragma unroll
            for (int j = 0; j < 2; ++j)
                acc[i][j] = __builtin_amdgcn_mfma_i32_16x16x64_i8(af[i], bf[j], acc[i][j], 0, 0, 0);
    }

    // epilogue: per-lane best over its 32 rows, then cross-quad via LDS
#pragma unroll
    for (int j = 0; j < 2; ++j) {
        unsigned long long bp = 0ull;
#pragma unroll
        for (int i = 0; i < 8; ++i)
#pragma unroll
            for (int r = 0; r < 4; ++r) {
                int grow = m0 + i * 16 + quad * 4 + r;
                unsigned long long pk =
                    (((unsigned long long)(uint32_t)acc[i][j][r]) << 32) |
                    (unsigned long long)(uint32_t)(511 - grow);
                bp = pk > bp ? pk : bp;
            }
        red[(wn * 32 + j * 16 + l15) * 4 + quad] = bp;
    }
    __syncthreads();
    if (tid < 128) {
        unsigned long long b = red[tid * 4];
#pragma unroll
        for (int u = 1; u < 4; ++u) {
            unsigned long long v = red[tid * 4 + u];
            b = v > b ? v : b;
        }
        atomicMax(&partial[col0 + tid], b);
    }
}

// ---------------------------------------------------------------- fire + scan (out zeroed in prep; verified R18)
__global__ __launch_bounds__(256) void k_firescan(
    const unsigned long long* __restrict__ partial, float* __restrict__ out)
{
    __shared__ int argL[576];
    __shared__ unsigned long long fm[9];
    const int b = blockIdx.x, tid = threadIdx.x;
    const int lane = tid & 63, wv = tid >> 6;

    // fire: 9 chunks of 64 t (chunk = p*4 + wave)
#pragma unroll
    for (int p = 0; p < 3; ++p) {
        int chunk = p * 4 + wv;
        if (chunk < 9) {                               // wave-uniform branch
            int t = chunk * 64 + lane;
            int col = b * TPAD + (t < TPAD ? t : TPAD - 1);
            unsigned long long pv = partial[col];
            int best = (int)(pv >> 32);
            argL[t] = 511 - (int)(pv & 0xFFFFFFFFull);
            unsigned long long f = __ballot((t < TP) && (best > 40));
            if (lane == 0) fm[chunk] = f;
        }
    }
    __syncthreads();

    if (tid == 0) {
        unsigned short ts[26];
        int nf = 0, dep = 0;
        for (int c = 0; c < 9; ++c) {
            unsigned long long mm = fm[c];
            int pos = 0;
            while (pos < 64) {
                if (dep > 0) {
                    int adv = dep < (64 - pos) ? dep : (64 - pos);
                    dep -= adv; pos += adv; mm >>= adv;    // adv <= 21 < 64
                    continue;
                }
                if (mm == 0) break;
                int z = __builtin_ctzll(mm);
                pos += z; mm >>= z;
                ts[nf++] = (unsigned short)(c * 64 + pos);
                dep = 21; ++pos; mm >>= 1;
            }
        }
        for (int i = 0; i < nf; ++i) {
            int t = ts[i];
            out[(size_t)b * (NEURONS * TP) + (size_t)argL[t] * TP + t] = 1.0f;
        }
    }
}

extern "C" void kernel_launch(void* const* d_in, const int* in_sizes, int n_in,
                              void* d_out, int out_size, void* d_ws, size_t ws_size,
                              hipStream_t stream) {
    const float* x      = (const float*)d_in[0];
    const int*   weight = (const int*)d_in[1];
    const int*   wk     = (const int*)d_in[2];

    char* ws = (char*)d_ws;
    uint2*              Apk     = (uint2*)(ws);                        // 3,211,264 B
    uint32_t*           xbT     = (uint32_t*)(ws + 3211264);           // 3,612,672 B
    unsigned long long* partial = (unsigned long long*)(ws + 6823936); //   270,336 B
    // total ws need: 7,094,272 B

    float* out = (float*)d_out;

    // 3 dispatches: prep (apack + xbitsT + partial-zero + out-zero),
    // fused GEMM, firescan.
    k_prep<<<5216, 256, 0, stream>>>(weight, Apk, x, xbT, partial, (float4*)out);
    k_gemm_fused2<<<1056, 256, 0, stream>>>((const i32x4*)Apk, xbT, wk, partial);
    k_firescan<<<BATCH, 256, 0, stream>>>(partial, out);
}